// Round 8
// baseline (540.844 us; speedup 1.0000x reference)
//
#include <hip/hip_runtime.h>

namespace {
constexpr int kNDrug = 50000;
constexpr int kNDis  = 50000;
constexpr int kE     = 800000;
constexpr int kR     = 2;
constexpr int kIn    = 2048;   // IN_UNITS
constexpr int kMsg   = 32;     // AGG_UNITS / 3
constexpr int kAgg   = 96;     // AGG_UNITS
constexpr int kOut   = 64;     // OUT_UNITS
constexpr int kBasis = 4;
constexpr float kSlope = 0.1f; // LeakyReLU slope
constexpr int kNTot  = kNDis + kNDrug;            // [0,kNDis)=dis nodes, rest drug nodes
constexpr int kBN    = 102;                       // nodes per bucket -> 981 blocks <= 1024
                                                  // (4-resident x 256 CU) => zero tail, 32 waves/CU
constexpr int kNBuck = (kNTot + kBN - 1) / kBN;   // 981
constexpr int kSegCap = 3536;                     // entries/bucket (mean 3264, +4.8 sigma), 16-mult
constexpr int kFifoCap = 37;                      // LDS FIFO depth per bucket in bin_pass
constexpr int kBinBlocks = 64;                    // binning blocks (1024 thr each)
constexpr int kOvfCap = 4096;                     // overflow list capacity
constexpr int kNPW   = 13;                        // ceil(kBN/8) nodes per wave in gather
constexpr int kSent  = 16;                        // sentinel pad (covers dual-chain lookahead)
}

// ---------------- one-shot init: W = att@basis, cursors ----------------
__global__ __launch_bounds__(256) void setup_all(const float* __restrict__ att,
                                                 const float* __restrict__ basis,
                                                 float* __restrict__ W,
                                                 int* __restrict__ bcur,
                                                 int* __restrict__ ovfCnt) {
    constexpr int per_r = kIn * kMsg;
    const int blk = blockIdx.x;
    const int t = threadIdx.x;
    if (blk < 512) {                       // W: 2*2048*32 = 131072 elems
        int idx = blk * 256 + t;
        int r = idx / per_r;
        int ic = idx - r * per_r;
        float acc = 0.f;
#pragma unroll
        for (int b = 0; b < kBasis; ++b)
            acc += att[r * kBasis + b] * basis[b * per_r + ic];
        W[idx] = acc;
    } else {                               // blocks 512..515: bcur init; 512/t0: ovfCnt
        int i = (blk - 512) * 256 + t;
        if (i < kNBuck) bcur[i] = i * kSegCap;
        if (blk == 512 && t == 0) *ovfCnt = 0;
    }
}

// ---------------- LDS-FIFO binning (64 blocks x 1024 threads) ----------------
// Per-bucket LDS FIFOs; flush in fixed 32-entry (128B) aligned full-line units,
// one global atomic per flush. Rare FIFO overflows go to the ovf list
// (re-inserted by ovf_drain). FifoCap 37 (slack 5 above threshold): a handful
// of transient overshoots per run take the ovf path -- correct by construction.
// entry = gnode (16b) | rating (bit16) | node-rel-in-bucket (bits 17..23)
__global__ __launch_bounds__(1024) void bin_pass(const int* __restrict__ esrc,
                                                 const int* __restrict__ edst,
                                                 int* __restrict__ bcur,
                                                 unsigned* __restrict__ bin,
                                                 int* __restrict__ ovfCnt,
                                                 unsigned* __restrict__ ovfE,
                                                 int* __restrict__ ovfB) {
    __shared__ unsigned fifo[kNBuck][kFifoCap];  // 145.2 KB
    __shared__ int fcnt[kNBuck];
    __shared__ int flList[kNBuck], flAmt[kNBuck], flPos[kNBuck];
    __shared__ int nFl;

    const int t = threadIdx.x;
    for (int i = t; i < kNBuck; i += 1024) fcnt[i] = 0;

    const int total = kR * kE;
    const int per = (total + kBinBlocks - 1) / kBinBlocks;   // 25000 edges
    const int e0 = blockIdx.x * per;
    const int e1 = (e0 + per < total) ? e0 + per : total;
    __syncthreads();

    auto place = [&](int node, int gn, int r) {
        int bb = node / kBN;
        int rel = node - bb * kBN;
        unsigned ent = (unsigned)gn | ((unsigned)r << 16) | ((unsigned)rel << 17);
        int pos = atomicAdd(&fcnt[bb], 1);
        if (pos < kFifoCap) {
            fifo[bb][pos] = ent;
        } else {  // rare transient overshoot
            int s = atomicAdd(ovfCnt, 1);
            if (s < kOvfCap) { ovfE[s] = ent; ovfB[s] = bb; }
        }
    };

    for (int base = e0; base < e1; base += 1024) {
        int idx = base + t;
        if (idx < e1) {
            int r = (idx >= kE) ? 1 : 0;
            int src = esrc[idx], dst = edst[idx];
            place(dst, src, r);            // dis-side entry
            place(kNDis + src, dst, r);    // drug-side entry
        }
        if (t == 0) nFl = 0;
        __syncthreads();
        // flush-list build: fixed amount 32 per flush
        for (int bb = t; bb < kNBuck; bb += 1024) {
            int c = fcnt[bb]; if (c > kFifoCap) c = kFifoCap;
            if (c >= 32) {
                int slot = atomicAdd(&nFl, 1);
                flList[slot] = bb;
                flPos[slot] = atomicAdd(&bcur[bb], 32);   // stays 32-aligned
            }
        }
        __syncthreads();
        // full-line copies LDS -> bin (one 128B line per flush)
        {
            const int n = nFl;
            const int hw = t >> 5, ln = t & 31;
            for (int it = hw; it < n; it += 32) {
                int bb = flList[it], gp = flPos[it];
                int capEnd = bb * kSegCap + kSegCap;
                unsigned ent = fifo[bb][ln];
                int d = gp + ln;
                if (d < capEnd) bin[d] = ent;
                else { int s = atomicAdd(ovfCnt, 1);
                       if (s < kOvfCap) { ovfE[s] = ent; ovfB[s] = bb; } }
            }
        }
        __syncthreads();
        // compact leftovers (<=5) to FIFO front
        for (int bb = t; bb < kNBuck; bb += 1024) {
            int c = fcnt[bb]; if (c > kFifoCap) c = kFifoCap;
            if (c >= 32) {
                for (int j = 32; j < c; ++j) fifo[bb][j - 32] = fifo[bb][j];
                fcnt[bb] = c - 32;
            } else {
                fcnt[bb] = c;
            }
        }
        __syncthreads();
    }

    // final drain: partial flushes of the <=kFifoCap-entry tails
    if (t == 0) nFl = 0;
    __syncthreads();
    for (int bb = t; bb < kNBuck; bb += 1024) {
        int c = fcnt[bb]; if (c > kFifoCap) c = kFifoCap;
        if (c) {
            int slot = atomicAdd(&nFl, 1);
            flList[slot] = bb; flAmt[slot] = c;
            flPos[slot] = atomicAdd(&bcur[bb], c);
        }
    }
    __syncthreads();
    const int n = nFl;
    const int hw = t >> 5, ln = t & 31;
    for (int it = hw; it < n; it += 32) {
        int bb = flList[it], f = flAmt[it], gp = flPos[it];
        int capEnd = bb * kSegCap + kSegCap;
        for (int j = ln; j < f; j += 32) {
            unsigned ent = fifo[bb][j];
            int d = gp + j;
            if (d < capEnd) bin[d] = ent;
            else { int s = atomicAdd(ovfCnt, 1);
                   if (s < kOvfCap) { ovfE[s] = ent; ovfB[s] = bb; } }
        }
    }
}

// ---------------- re-insert overflow entries into bin where room remains ----------------
__global__ __launch_bounds__(256) void ovf_drain(int* __restrict__ bcur,
                                                 unsigned* __restrict__ bin,
                                                 const int* __restrict__ ovfCnt,
                                                 const unsigned* __restrict__ ovfE,
                                                 int* __restrict__ ovfB) {
    int n = *ovfCnt; if (n > kOvfCap) n = kOvfCap;
    int i = blockIdx.x * 256 + threadIdx.x;
    if (i >= n) return;
    int bb = ovfB[i];
    int pos = atomicAdd(&bcur[bb], 1);
    if (pos < bb * kSegCap + kSegCap) { bin[pos] = ovfE[i]; ovfB[i] = -1; }
}

// ---- dual-chain 4-stage pipeline pieces (stride 4 in sp-index, offsets 0 / 2) ----
#define ACC_PRO(sp_, OFS_, e1_, e2_, i10_, i11_, i12_, c0_, c1_, w00_, w01_, w02_)      \
  { unsigned e0_ = (sp_)[OFS_]; e1_ = (sp_)[(OFS_) + 4]; e2_ = (sp_)[(OFS_) + 8];       \
    int g0_ = (int)(e0_ & 0xffffu);                                                     \
    int j0_ = fidxp[g0_*3], j1_ = fidxp[g0_*3+1], j2_ = fidxp[g0_*3+2];                 \
    c0_ = cjp[g0_];                                                                     \
    int g1_ = (int)(e1_ & 0xffffu);                                                     \
    i10_ = fidxp[g1_*3]; i11_ = fidxp[g1_*3+1]; i12_ = fidxp[g1_*3+2];                  \
    c1_ = cjp[g1_];                                                                     \
    const float* W0_ = W + (((e0_ >> 16) & 1u) * (unsigned)(kIn * kMsg));               \
    w00_ = W0_[(j0_ << 5) + fl]; w01_ = W0_[(j1_ << 5) + fl]; w02_ = W0_[(j2_ << 5) + fl]; }

#define ACC_BODY(sp_, OFS_, tt_, e1_, e2_, i10_, i11_, i12_, c0_, c1_, w00_, w01_, w02_, a0_, a1_, a2_) \
  { unsigned e3_ = (sp_)[(OFS_) + 4*(tt_) + 12];                                        \
    int g2_ = (int)(e2_ & 0xffffu);                                                     \
    int i20_ = fidxp[g2_*3], i21_ = fidxp[g2_*3+1], i22_ = fidxp[g2_*3+2];              \
    float c2_ = cjp[g2_];                                                               \
    const float* W1_ = W + (((e1_ >> 16) & 1u) * (unsigned)(kIn * kMsg));               \
    float w10_ = W1_[(i10_ << 5) + fl];                                                 \
    float w11_ = W1_[(i11_ << 5) + fl];                                                 \
    float w12_ = W1_[(i12_ << 5) + fl];                                                 \
    a0_ = fmaf(w00_, c0_, a0_); a1_ = fmaf(w01_, c0_, a1_); a2_ = fmaf(w02_, c0_, a2_); \
    e1_ = e2_; e2_ = e3_; i10_ = i20_; i11_ = i21_; i12_ = i22_;                        \
    c0_ = c1_; c1_ = c2_; w00_ = w10_; w01_ = w11_; w02_ = w12_; }

// ---------------- fused per-bucket gather + ci/LeakyReLU/FC ----------------
// One 512-thread block per 102-node bucket; LDS ~= 40.3 KB -> 4 blocks/CU
// residency (32 waves/CU) set by HARDWARE resources. __launch_bounds__(512,6):
// allocator sees an 85-VGPR budget (body uses ~40, no spills -- round 7's
// (512,8)=64-cap forced a 32-VGPR spilling allocation, 2x slower); residency
// still reaches 4 blocks/CU because 40 VGPR <= 64.
__global__ __launch_bounds__(512, 6) void gather_fused(
        const unsigned* __restrict__ bin,
        const int* __restrict__ bcur,
        const int* __restrict__ ovfCnt,
        const unsigned* __restrict__ ovfE,
        const int* __restrict__ ovfB,
        const float* __restrict__ W,
        const int* __restrict__ drug_idx, const int* __restrict__ dis_idx,
        const float* __restrict__ cj_drug, const float* __restrict__ cj_dis,
        const float* __restrict__ ci_drug, const float* __restrict__ ci_dis,
        const float* __restrict__ w_fc, const float* __restrict__ b_fc,
        float* __restrict__ out) {
    __shared__ float ws[kAgg * kOut];              // 24 KB
    __shared__ float bs[kOut];
    __shared__ unsigned stage[kSegCap + kSent];    // 13.9 KB
    __shared__ int h[kBN], lb[kBN];
    __shared__ int sbuf[kBN];
    __shared__ int sOvf;

    const int t = threadIdx.x;
    const int b = blockIdx.x;
    for (int i = t; i < kAgg * kOut; i += 512) ws[i] = w_fc[i];
    if (t < kOut) bs[t] = b_fc[t];
    if (t < kBN) h[t] = 0;
    if (t == 0) sOvf = (ovfCnt[0] < kOvfCap) ? ovfCnt[0] : kOvfCap;

    const int sb = b * kSegCap;
    __syncthreads();
    int seg = bcur[b] - sb;
    if (seg > kSegCap) seg = kSegCap;

    // histogram rel-node over the segment
    for (int i = t; i < seg; i += 512)
        atomicAdd(&h[bin[sb + i] >> 17], 1);
    __syncthreads();
    // scan of kBN counters (Hillis-Steele)
    if (t < kBN) sbuf[t] = h[t];
    __syncthreads();
    for (int o = 1; o < kBN; o <<= 1) {
        int x = 0;
        if (t < kBN && t >= o) x = sbuf[t - o];
        __syncthreads();
        if (t < kBN) sbuf[t] += x;
        __syncthreads();
    }
    if (t < kBN) { int ex = sbuf[t] - h[t]; lb[t] = ex; sbuf[t] = ex; }
    if (t < kSent) stage[seg + t] = 0;   // sentinel entries (loaded, never FMA'd)
    __syncthreads();
    // scatter into per-node-ordered LDS staging
    for (int i = t; i < seg; i += 512) {
        unsigned e = bin[sb + i];
        int pos = atomicAdd(&sbuf[e >> 17], 1);
        stage[pos] = e;
    }
    __syncthreads();

    const int wid  = t >> 6;
    const int lane = t & 63;
    const int half = lane >> 5;
    const int fl   = lane & 31;

    for (int i = 0; i < kNPW; ++i) {
        const int nl = wid * kNPW + i;
        if (nl >= kBN) break;    // wave-uniform
        const int g  = b * kBN + nl;
        if (g >= kNTot) break;   // wave-uniform; no block syncs below

        const int* fidxp;
        const float* cjp;
        float civ;
        size_t orow;
        if (g < kNDis) {         // dis dst node: gathers DRUG feats
            fidxp = drug_idx; cjp = cj_drug; civ = ci_dis[g];
            orow = (size_t)(kNDrug + g);
        } else {                 // drug dst node: gathers DIS feats
            fidxp = dis_idx;  cjp = cj_dis;  civ = ci_drug[g - kNDis];
            orow = (size_t)(g - kNDis);
        }

        const int base = lb[nl];
        const int deg  = h[nl];
        const unsigned* sp = stage + base + half;
        const int n  = (deg - half + 1) >> 1;   // this half's entry count
        const int nA = (n + 1) >> 1;            // chain A: half-entries 0,2,4,..
        const int nB = n >> 1;                  // chain B: half-entries 1,3,5,..

        float a0A = 0.f, a1A = 0.f, a2A = 0.f;
        float a0B = 0.f, a1B = 0.f, a2B = 0.f;
        unsigned eA1, eA2, eB1, eB2;
        int iA0, iA1, iA2, iB0, iB1, iB2;
        float cA0, cA1, cB0, cB1;
        float wA0, wA1, wA2, wB0, wB1, wB2;

        ACC_PRO(sp, 0, eA1, eA2, iA0, iA1, iA2, cA0, cA1, wA0, wA1, wA2);
        ACC_PRO(sp, 2, eB1, eB2, iB0, iB1, iB2, cB0, cB1, wB0, wB1, wB2);

        int tt = 0;
        for (; tt < nB; ++tt) {
            ACC_BODY(sp, 0, tt, eA1, eA2, iA0, iA1, iA2, cA0, cA1, wA0, wA1, wA2,
                     a0A, a1A, a2A);
            ACC_BODY(sp, 2, tt, eB1, eB2, iB0, iB1, iB2, cB0, cB1, wB0, wB1, wB2,
                     a0B, a1B, a2B);
        }
        if (tt < nA) {
            ACC_BODY(sp, 0, tt, eA1, eA2, iA0, iA1, iA2, cA0, cA1, wA0, wA1, wA2,
                     a0A, a1A, a2A);
        }

        float a0 = a0A + a0B, a1 = a1A + a1B, a2 = a2A + a2B;

        if (sOvf > 0) {          // rare leftover overflow entries
            for (int j = half; j < sOvf; j += 2) {
                int bb = ovfB[j];
                if (bb == b && (int)(ovfE[j] >> 17) == nl) {
                    unsigned e = ovfE[j];
                    int gg = (int)(e & 0xffffu);
                    const float* Wr = W + (((e >> 16) & 1u) * (unsigned)(kIn * kMsg));
                    float c = cjp[gg];
                    a0 = fmaf(Wr[(fidxp[gg * 3]     << 5) + fl], c, a0);
                    a1 = fmaf(Wr[(fidxp[gg * 3 + 1] << 5) + fl], c, a1);
                    a2 = fmaf(Wr[(fidxp[gg * 3 + 2] << 5) + fl], c, a2);
                }
            }
        }

        a0 += __shfl_xor(a0, 32);
        a1 += __shfl_xor(a1, 32);
        a2 += __shfl_xor(a2, 32);

        a0 *= civ; a1 *= civ; a2 *= civ;
        a0 = (a0 >= 0.f) ? a0 : kSlope * a0;
        a1 = (a1 >= 0.f) ? a1 : kSlope * a1;
        a2 = (a2 >= 0.f) ? a2 : kSlope * a2;

        float acc = bs[lane];
#pragma unroll
        for (int k = 0; k < 32; ++k)
            acc = fmaf(__shfl(a0, k), ws[k * kOut + lane], acc);
#pragma unroll
        for (int k = 0; k < 32; ++k)
            acc = fmaf(__shfl(a1, k), ws[(32 + k) * kOut + lane], acc);
#pragma unroll
        for (int k = 0; k < 32; ++k)
            acc = fmaf(__shfl(a2, k), ws[(64 + k) * kOut + lane], acc);
        out[orow * kOut + lane] = acc;
    }
}

// ---------------- fallback path (R1 atomic scatter, tiny-ws only) ----------------
__global__ __launch_bounds__(256) void build_W_fb(const float* __restrict__ att,
                                                  const float* __restrict__ basis,
                                                  float* __restrict__ W) {
    constexpr int per_r = kIn * kMsg;
    int idx = blockIdx.x * blockDim.x + threadIdx.x;
    if (idx >= kR * per_r) return;
    int r = idx / per_r;
    int ic = idx - r * per_r;
    float acc = 0.f;
#pragma unroll
    for (int b = 0; b < kBasis; ++b)
        acc += att[r * kBasis + b] * basis[b * per_r + ic];
    W[idx] = acc;
}

__global__ __launch_bounds__(256) void edge_scatter(
        const float* __restrict__ W,
        const int* __restrict__ gnode,
        const int* __restrict__ snode,
        const int* __restrict__ fidx,
        const float* __restrict__ cj,
        float* __restrict__ h) {
    const int r = blockIdx.y;
    long tid = (long)blockIdx.x * blockDim.x + threadIdx.x;
    const int lane = (int)(tid & 31);
    const long e = tid >> 5;
    if (e >= kE) return;
    const int g = gnode[(long)r * kE + e];
    const int s = snode[(long)r * kE + e];
    const int i0 = fidx[g * 3 + 0];
    const int i1 = fidx[g * 3 + 1];
    const int i2 = fidx[g * 3 + 2];
    const float c = cj[g];
    const float* Wr = W + (size_t)r * kIn * kMsg;
    float* outp = h + (size_t)s * kAgg;
    atomicAdd(&outp[lane],            Wr[(size_t)i0 * kMsg + lane] * c);
    atomicAdd(&outp[kMsg + lane],     Wr[(size_t)i1 * kMsg + lane] * c);
    atomicAdd(&outp[2 * kMsg + lane], Wr[(size_t)i2 * kMsg + lane] * c);
}

__global__ __launch_bounds__(256) void fc_fused(const float* __restrict__ h,
                                                const float* __restrict__ ci,
                                                const float* __restrict__ w_fc,
                                                const float* __restrict__ b_fc,
                                                float* __restrict__ out, int nrows) {
    __shared__ float ws[kAgg * kOut];
    __shared__ float bs[kOut];
    const int lt = threadIdx.y * blockDim.x + threadIdx.x;
    for (int i = lt; i < kAgg * kOut; i += blockDim.x * blockDim.y)
        ws[i] = w_fc[i];
    if (lt < kOut) bs[lt] = b_fc[lt];
    __syncthreads();
    const int row = blockIdx.x * blockDim.y + threadIdx.y;
    if (row >= nrows) return;
    const int col = threadIdx.x;
    const float c = ci[row];
    const float* hr = h + (size_t)row * kAgg;
    float acc = bs[col];
#pragma unroll 8
    for (int k = 0; k < kAgg; ++k) {
        float a = hr[k] * c;
        a = (a >= 0.f) ? a : kSlope * a;
        acc += a * ws[k * kOut + col];
    }
    out[(size_t)row * kOut + col] = acc;
}

extern "C" void kernel_launch(void* const* d_in, const int* in_sizes, int n_in,
                              void* d_out, int out_size, void* d_ws, size_t ws_size,
                              hipStream_t stream) {
    const int*   drug_idx = (const int*)d_in[0];
    const int*   dis_idx  = (const int*)d_in[1];
    const int*   edge_src = (const int*)d_in[2];
    const int*   edge_dst = (const int*)d_in[3];
    const float* cj_drug  = (const float*)d_in[4];
    const float* ci_drug  = (const float*)d_in[5];
    const float* cj_dis   = (const float*)d_in[6];
    const float* ci_dis   = (const float*)d_in[7];
    const float* att      = (const float*)d_in[8];
    const float* basis    = (const float*)d_in[9];
    const float* w_fc     = (const float*)d_in[10];
    const float* b_fc     = (const float*)d_in[11];
    float* out = (float*)d_out;

    auto align256 = [](size_t x) { return (x + 255) & ~(size_t)255; };
    const size_t Wb    = align256((size_t)kR * kIn * kMsg * sizeof(float));     // 512 KB
    const size_t bcB   = align256((size_t)kNBuck * sizeof(int));
    const size_t ocB   = align256(sizeof(int));
    const size_t oeB   = align256((size_t)kOvfCap * sizeof(unsigned));          // 16 KB
    const size_t obB   = align256((size_t)kOvfCap * sizeof(int));               // 16 KB
    const size_t binB  = align256((size_t)kNBuck * kSegCap * sizeof(unsigned)); // ~13.88 MB
    const size_t needNew = Wb + bcB + ocB + oeB + obB + binB;                   // ~14.44 MB

    char* p = (char*)d_ws;
    float*    W      = (float*)p;        p += Wb;
    int*      bcur   = (int*)p;          p += bcB;
    int*      ovfCnt = (int*)p;          p += ocB;
    unsigned* ovfE   = (unsigned*)p;     p += oeB;
    int*      ovfB   = (int*)p;          p += obB;
    unsigned* bin    = (unsigned*)p;

    if (ws_size >= needNew) {
        setup_all<<<dim3(516), 256, 0, stream>>>(att, basis, W, bcur, ovfCnt);
        bin_pass<<<dim3(kBinBlocks), 1024, 0, stream>>>(edge_src, edge_dst,
                                                        bcur, bin, ovfCnt, ovfE, ovfB);
        ovf_drain<<<dim3((kOvfCap + 255) / 256), 256, 0, stream>>>(bcur, bin,
                                                                   ovfCnt, ovfE, ovfB);
        gather_fused<<<dim3(kNBuck), 512, 0, stream>>>(bin, bcur, ovfCnt, ovfE, ovfB,
                                                       W, drug_idx, dis_idx,
                                                       cj_drug, cj_dis,
                                                       ci_drug, ci_dis,
                                                       w_fc, b_fc, out);
    } else {
        // fallback: R1 phased atomic-scatter path (needs ~19.7 MB)
        build_W_fb<<<dim3((kR * kIn * kMsg + 255) / 256), 256, 0, stream>>>(att, basis, W);
        const size_t hB = (size_t)kNDrug * kAgg * sizeof(float);
        float* h = (float*)((char*)d_ws + Wb);
        const int scat_blocks = (int)(((long)kE * 32 + 255) / 256);
        const dim3 scat_grid(scat_blocks, kR);
        hipMemsetAsync(h, 0, hB, stream);
        edge_scatter<<<scat_grid, 256, 0, stream>>>(W, edge_dst, edge_src,
                                                    dis_idx, cj_dis, h);
        fc_fused<<<dim3((kNDrug + 3) / 4), dim3(64, 4), 0, stream>>>(
            h, ci_drug, w_fc, b_fc, out, kNDrug);
        hipMemsetAsync(h, 0, hB, stream);
        edge_scatter<<<scat_grid, 256, 0, stream>>>(W, edge_src, edge_dst,
                                                    drug_idx, cj_drug, h);
        fc_fused<<<dim3((kNDis + 3) / 4), dim3(64, 4), 0, stream>>>(
            h, ci_dis, w_fc, b_fc, out + (size_t)kNDrug * kOut, kNDis);
    }
}

// Round 9
// 239.631 us; speedup vs baseline: 2.2570x; 2.2570x over previous
//
#include <hip/hip_runtime.h>

namespace {
constexpr int kNDrug = 50000;
constexpr int kNDis  = 50000;
constexpr int kE     = 800000;
constexpr int kR     = 2;
constexpr int kIn    = 2048;   // IN_UNITS
constexpr int kMsg   = 32;     // AGG_UNITS / 3
constexpr int kAgg   = 96;     // AGG_UNITS
constexpr int kOut   = 64;     // OUT_UNITS
constexpr int kBasis = 4;
constexpr float kSlope = 0.1f; // LeakyReLU slope
constexpr int kNTot  = kNDis + kNDrug;            // [0,kNDis)=dis nodes, rest drug nodes
constexpr int kBN    = 102;                       // nodes per bucket -> 981 blocks <= 1024
constexpr int kNBuck = (kNTot + kBN - 1) / kBN;   // 981
constexpr int kSegCap = 3536;                     // entries/bucket (mean 3264, +4.8 sigma), 16-mult
constexpr int kFifoCap = 37;                      // LDS FIFO depth per bucket in bin_pass
constexpr int kFlushThr = 16;                     // flush unit = 16 entries = 64B; slack 21 above
                                                  // threshold -> FIFO overflow statistically never
                                                  // (round 7/8 regression: slack 5 -> thousands of
                                                  // ovf entries -> per-node ovf scan cost +330us)
constexpr int kBinBlocks = 64;                    // binning blocks (1024 thr each)
constexpr int kOvfCap = 4096;                     // overflow list capacity
constexpr int kNPW   = 13;                        // ceil(kBN/8) nodes per wave in gather
constexpr int kSent  = 16;                        // sentinel pad (covers dual-chain lookahead)
}

// ---------------- one-shot init: W = att@basis, cursors ----------------
__global__ __launch_bounds__(256) void setup_all(const float* __restrict__ att,
                                                 const float* __restrict__ basis,
                                                 float* __restrict__ W,
                                                 int* __restrict__ bcur,
                                                 int* __restrict__ ovfCnt) {
    constexpr int per_r = kIn * kMsg;
    const int blk = blockIdx.x;
    const int t = threadIdx.x;
    if (blk < 512) {                       // W: 2*2048*32 = 131072 elems
        int idx = blk * 256 + t;
        int r = idx / per_r;
        int ic = idx - r * per_r;
        float acc = 0.f;
#pragma unroll
        for (int b = 0; b < kBasis; ++b)
            acc += att[r * kBasis + b] * basis[b * per_r + ic];
        W[idx] = acc;
    } else {                               // blocks 512..515: bcur init; 512/t0: ovfCnt
        int i = (blk - 512) * 256 + t;
        if (i < kNBuck) bcur[i] = i * kSegCap;
        if (blk == 512 && t == 0) *ovfCnt = 0;
    }
}

// ---------------- LDS-FIFO binning (64 blocks x 1024 threads) ----------------
// Per-bucket LDS FIFOs; flush in fixed 16-entry (64B) aligned units, one global
// atomic per flush. bin is L2/L3-resident so 64B units don't trigger HBM
// partial-line writebacks. FIFO cap 37 with threshold 16 -> slack 21 -> the
// ovf path is statistically never taken (the round-7/8 lesson).
// entry = gnode (16b) | rating (bit16) | node-rel-in-bucket (bits 17..23)
__global__ __launch_bounds__(1024) void bin_pass(const int* __restrict__ esrc,
                                                 const int* __restrict__ edst,
                                                 int* __restrict__ bcur,
                                                 unsigned* __restrict__ bin,
                                                 int* __restrict__ ovfCnt,
                                                 unsigned* __restrict__ ovfE,
                                                 int* __restrict__ ovfB) {
    __shared__ unsigned fifo[kNBuck][kFifoCap];  // 145.2 KB
    __shared__ int fcnt[kNBuck];
    __shared__ int flList[kNBuck], flAmt[kNBuck], flPos[kNBuck];
    __shared__ int nFl;

    const int t = threadIdx.x;
    for (int i = t; i < kNBuck; i += 1024) fcnt[i] = 0;

    const int total = kR * kE;
    const int per = (total + kBinBlocks - 1) / kBinBlocks;   // 25000 edges
    const int e0 = blockIdx.x * per;
    const int e1 = (e0 + per < total) ? e0 + per : total;
    __syncthreads();

    auto place = [&](int node, int gn, int r) {
        int bb = node / kBN;
        int rel = node - bb * kBN;
        unsigned ent = (unsigned)gn | ((unsigned)r << 16) | ((unsigned)rel << 17);
        int pos = atomicAdd(&fcnt[bb], 1);
        if (pos < kFifoCap) {
            fifo[bb][pos] = ent;
        } else {  // statistically never (slack 21)
            int s = atomicAdd(ovfCnt, 1);
            if (s < kOvfCap) { ovfE[s] = ent; ovfB[s] = bb; }
        }
    };

    for (int base = e0; base < e1; base += 1024) {
        int idx = base + t;
        if (idx < e1) {
            int r = (idx >= kE) ? 1 : 0;
            int src = esrc[idx], dst = edst[idx];
            place(dst, src, r);            // dis-side entry
            place(kNDis + src, dst, r);    // drug-side entry
        }
        if (t == 0) nFl = 0;
        __syncthreads();
        // flush-list build: fixed amount kFlushThr per flush
        for (int bb = t; bb < kNBuck; bb += 1024) {
            int c = fcnt[bb]; if (c > kFifoCap) c = kFifoCap;
            if (c >= kFlushThr) {
                int slot = atomicAdd(&nFl, 1);
                flList[slot] = bb;
                flPos[slot] = atomicAdd(&bcur[bb], kFlushThr);   // stays 16-aligned
            }
        }
        __syncthreads();
        // 64B-unit copies LDS -> bin (16-lane groups)
        {
            const int n = nFl;
            const int grp = t >> 4, ln = t & 15;
            for (int it = grp; it < n; it += 64) {
                int bb = flList[it], gp = flPos[it];
                int capEnd = bb * kSegCap + kSegCap;
                unsigned ent = fifo[bb][ln];
                int d = gp + ln;
                if (d < capEnd) bin[d] = ent;
                else { int s = atomicAdd(ovfCnt, 1);
                       if (s < kOvfCap) { ovfE[s] = ent; ovfB[s] = bb; } }
            }
        }
        __syncthreads();
        // compact leftovers (<=21) to FIFO front
        for (int bb = t; bb < kNBuck; bb += 1024) {
            int c = fcnt[bb]; if (c > kFifoCap) c = kFifoCap;
            if (c >= kFlushThr) {
                for (int j = kFlushThr; j < c; ++j) fifo[bb][j - kFlushThr] = fifo[bb][j];
                fcnt[bb] = c - kFlushThr;
            } else {
                fcnt[bb] = c;
            }
        }
        __syncthreads();
    }

    // final drain: partial flushes of the <=kFifoCap-entry tails
    if (t == 0) nFl = 0;
    __syncthreads();
    for (int bb = t; bb < kNBuck; bb += 1024) {
        int c = fcnt[bb]; if (c > kFifoCap) c = kFifoCap;
        if (c) {
            int slot = atomicAdd(&nFl, 1);
            flList[slot] = bb; flAmt[slot] = c;
            flPos[slot] = atomicAdd(&bcur[bb], c);
        }
    }
    __syncthreads();
    const int n = nFl;
    const int grp = t >> 4, ln = t & 15;
    for (int it = grp; it < n; it += 64) {
        int bb = flList[it], f = flAmt[it], gp = flPos[it];
        int capEnd = bb * kSegCap + kSegCap;
        for (int j = ln; j < f; j += 16) {
            unsigned ent = fifo[bb][j];
            int d = gp + j;
            if (d < capEnd) bin[d] = ent;
            else { int s = atomicAdd(ovfCnt, 1);
                   if (s < kOvfCap) { ovfE[s] = ent; ovfB[s] = bb; } }
        }
    }
}

// ---------------- re-insert overflow entries into bin where room remains ----------------
__global__ __launch_bounds__(256) void ovf_drain(int* __restrict__ bcur,
                                                 unsigned* __restrict__ bin,
                                                 const int* __restrict__ ovfCnt,
                                                 const unsigned* __restrict__ ovfE,
                                                 int* __restrict__ ovfB) {
    int n = *ovfCnt; if (n > kOvfCap) n = kOvfCap;
    int i = blockIdx.x * 256 + threadIdx.x;
    if (i >= n) return;
    int bb = ovfB[i];
    int pos = atomicAdd(&bcur[bb], 1);
    if (pos < bb * kSegCap + kSegCap) { bin[pos] = ovfE[i]; ovfB[i] = -1; }
}

// ---- dual-chain 4-stage pipeline pieces (stride 4 in sp-index, offsets 0 / 2) ----
#define ACC_PRO(sp_, OFS_, e1_, e2_, i10_, i11_, i12_, c0_, c1_, w00_, w01_, w02_)      \
  { unsigned e0_ = (sp_)[OFS_]; e1_ = (sp_)[(OFS_) + 4]; e2_ = (sp_)[(OFS_) + 8];       \
    int g0_ = (int)(e0_ & 0xffffu);                                                     \
    int j0_ = fidxp[g0_*3], j1_ = fidxp[g0_*3+1], j2_ = fidxp[g0_*3+2];                 \
    c0_ = cjp[g0_];                                                                     \
    int g1_ = (int)(e1_ & 0xffffu);                                                     \
    i10_ = fidxp[g1_*3]; i11_ = fidxp[g1_*3+1]; i12_ = fidxp[g1_*3+2];                  \
    c1_ = cjp[g1_];                                                                     \
    const float* W0_ = W + (((e0_ >> 16) & 1u) * (unsigned)(kIn * kMsg));               \
    w00_ = W0_[(j0_ << 5) + fl]; w01_ = W0_[(j1_ << 5) + fl]; w02_ = W0_[(j2_ << 5) + fl]; }

#define ACC_BODY(sp_, OFS_, tt_, e1_, e2_, i10_, i11_, i12_, c0_, c1_, w00_, w01_, w02_, a0_, a1_, a2_) \
  { unsigned e3_ = (sp_)[(OFS_) + 4*(tt_) + 12];                                        \
    int g2_ = (int)(e2_ & 0xffffu);                                                     \
    int i20_ = fidxp[g2_*3], i21_ = fidxp[g2_*3+1], i22_ = fidxp[g2_*3+2];              \
    float c2_ = cjp[g2_];                                                               \
    const float* W1_ = W + (((e1_ >> 16) & 1u) * (unsigned)(kIn * kMsg));               \
    float w10_ = W1_[(i10_ << 5) + fl];                                                 \
    float w11_ = W1_[(i11_ << 5) + fl];                                                 \
    float w12_ = W1_[(i12_ << 5) + fl];                                                 \
    a0_ = fmaf(w00_, c0_, a0_); a1_ = fmaf(w01_, c0_, a1_); a2_ = fmaf(w02_, c0_, a2_); \
    e1_ = e2_; e2_ = e3_; i10_ = i20_; i11_ = i21_; i12_ = i22_;                        \
    c0_ = c1_; c1_ = c2_; w00_ = w10_; w01_ = w11_; w02_ = w12_; }

// ---------------- fused per-bucket gather + ci/LeakyReLU/FC ----------------
// One 512-thread block per 102-node bucket; LDS ~= 40.3 KB -> 4 blocks/CU by
// hardware resources (40 VGPR <= 64). __launch_bounds__(512,6): 85-VGPR
// allocator budget, body uses ~40, no spills (the (512,8)=64-cap forced a
// spilling 32-VGPR allocation in round 7).
__global__ __launch_bounds__(512, 6) void gather_fused(
        const unsigned* __restrict__ bin,
        const int* __restrict__ bcur,
        const int* __restrict__ ovfCnt,
        const unsigned* __restrict__ ovfE,
        const int* __restrict__ ovfB,
        const float* __restrict__ W,
        const int* __restrict__ drug_idx, const int* __restrict__ dis_idx,
        const float* __restrict__ cj_drug, const float* __restrict__ cj_dis,
        const float* __restrict__ ci_drug, const float* __restrict__ ci_dis,
        const float* __restrict__ w_fc, const float* __restrict__ b_fc,
        float* __restrict__ out) {
    __shared__ float ws[kAgg * kOut];              // 24 KB
    __shared__ float bs[kOut];
    __shared__ unsigned stage[kSegCap + kSent];    // 13.9 KB
    __shared__ int h[kBN], lb[kBN];
    __shared__ int sbuf[kBN];
    __shared__ int sOvf;

    const int t = threadIdx.x;
    const int b = blockIdx.x;
    for (int i = t; i < kAgg * kOut; i += 512) ws[i] = w_fc[i];
    if (t < kOut) bs[t] = b_fc[t];
    if (t < kBN) h[t] = 0;
    if (t == 0) sOvf = (ovfCnt[0] < kOvfCap) ? ovfCnt[0] : kOvfCap;

    const int sb = b * kSegCap;
    __syncthreads();
    int seg = bcur[b] - sb;
    if (seg > kSegCap) seg = kSegCap;

    // histogram rel-node over the segment
    for (int i = t; i < seg; i += 512)
        atomicAdd(&h[bin[sb + i] >> 17], 1);
    __syncthreads();
    // scan of kBN counters (Hillis-Steele)
    if (t < kBN) sbuf[t] = h[t];
    __syncthreads();
    for (int o = 1; o < kBN; o <<= 1) {
        int x = 0;
        if (t < kBN && t >= o) x = sbuf[t - o];
        __syncthreads();
        if (t < kBN) sbuf[t] += x;
        __syncthreads();
    }
    if (t < kBN) { int ex = sbuf[t] - h[t]; lb[t] = ex; sbuf[t] = ex; }
    if (t < kSent) stage[seg + t] = 0;   // sentinel entries (loaded, never FMA'd)
    __syncthreads();
    // scatter into per-node-ordered LDS staging
    for (int i = t; i < seg; i += 512) {
        unsigned e = bin[sb + i];
        int pos = atomicAdd(&sbuf[e >> 17], 1);
        stage[pos] = e;
    }
    __syncthreads();

    const int wid  = t >> 6;
    const int lane = t & 63;
    const int half = lane >> 5;
    const int fl   = lane & 31;

    for (int i = 0; i < kNPW; ++i) {
        const int nl = wid * kNPW + i;
        if (nl >= kBN) break;    // wave-uniform
        const int g  = b * kBN + nl;
        if (g >= kNTot) break;   // wave-uniform; no block syncs below

        const int* fidxp;
        const float* cjp;
        float civ;
        size_t orow;
        if (g < kNDis) {         // dis dst node: gathers DRUG feats
            fidxp = drug_idx; cjp = cj_drug; civ = ci_dis[g];
            orow = (size_t)(kNDrug + g);
        } else {                 // drug dst node: gathers DIS feats
            fidxp = dis_idx;  cjp = cj_dis;  civ = ci_drug[g - kNDis];
            orow = (size_t)(g - kNDis);
        }

        const int base = lb[nl];
        const int deg  = h[nl];
        const unsigned* sp = stage + base + half;
        const int n  = (deg - half + 1) >> 1;   // this half's entry count
        const int nA = (n + 1) >> 1;            // chain A: half-entries 0,2,4,..
        const int nB = n >> 1;                  // chain B: half-entries 1,3,5,..

        float a0A = 0.f, a1A = 0.f, a2A = 0.f;
        float a0B = 0.f, a1B = 0.f, a2B = 0.f;
        unsigned eA1, eA2, eB1, eB2;
        int iA0, iA1, iA2, iB0, iB1, iB2;
        float cA0, cA1, cB0, cB1;
        float wA0, wA1, wA2, wB0, wB1, wB2;

        ACC_PRO(sp, 0, eA1, eA2, iA0, iA1, iA2, cA0, cA1, wA0, wA1, wA2);
        ACC_PRO(sp, 2, eB1, eB2, iB0, iB1, iB2, cB0, cB1, wB0, wB1, wB2);

        int tt = 0;
        for (; tt < nB; ++tt) {
            ACC_BODY(sp, 0, tt, eA1, eA2, iA0, iA1, iA2, cA0, cA1, wA0, wA1, wA2,
                     a0A, a1A, a2A);
            ACC_BODY(sp, 2, tt, eB1, eB2, iB0, iB1, iB2, cB0, cB1, wB0, wB1, wB2,
                     a0B, a1B, a2B);
        }
        if (tt < nA) {
            ACC_BODY(sp, 0, tt, eA1, eA2, iA0, iA1, iA2, cA0, cA1, wA0, wA1, wA2,
                     a0A, a1A, a2A);
        }

        float a0 = a0A + a0B, a1 = a1A + a1B, a2 = a2A + a2B;

        if (sOvf > 0) {          // statistically never non-zero now
            for (int j = half; j < sOvf; j += 2) {
                int bb = ovfB[j];
                if (bb == b && (int)(ovfE[j] >> 17) == nl) {
                    unsigned e = ovfE[j];
                    int gg = (int)(e & 0xffffu);
                    const float* Wr = W + (((e >> 16) & 1u) * (unsigned)(kIn * kMsg));
                    float c = cjp[gg];
                    a0 = fmaf(Wr[(fidxp[gg * 3]     << 5) + fl], c, a0);
                    a1 = fmaf(Wr[(fidxp[gg * 3 + 1] << 5) + fl], c, a1);
                    a2 = fmaf(Wr[(fidxp[gg * 3 + 2] << 5) + fl], c, a2);
                }
            }
        }

        a0 += __shfl_xor(a0, 32);
        a1 += __shfl_xor(a1, 32);
        a2 += __shfl_xor(a2, 32);

        a0 *= civ; a1 *= civ; a2 *= civ;
        a0 = (a0 >= 0.f) ? a0 : kSlope * a0;
        a1 = (a1 >= 0.f) ? a1 : kSlope * a1;
        a2 = (a2 >= 0.f) ? a2 : kSlope * a2;

        float acc = bs[lane];
#pragma unroll
        for (int k = 0; k < 32; ++k)
            acc = fmaf(__shfl(a0, k), ws[k * kOut + lane], acc);
#pragma unroll
        for (int k = 0; k < 32; ++k)
            acc = fmaf(__shfl(a1, k), ws[(32 + k) * kOut + lane], acc);
#pragma unroll
        for (int k = 0; k < 32; ++k)
            acc = fmaf(__shfl(a2, k), ws[(64 + k) * kOut + lane], acc);
        out[orow * kOut + lane] = acc;
    }
}

// ---------------- fallback path (R1 atomic scatter, tiny-ws only) ----------------
__global__ __launch_bounds__(256) void build_W_fb(const float* __restrict__ att,
                                                  const float* __restrict__ basis,
                                                  float* __restrict__ W) {
    constexpr int per_r = kIn * kMsg;
    int idx = blockIdx.x * blockDim.x + threadIdx.x;
    if (idx >= kR * per_r) return;
    int r = idx / per_r;
    int ic = idx - r * per_r;
    float acc = 0.f;
#pragma unroll
    for (int b = 0; b < kBasis; ++b)
        acc += att[r * kBasis + b] * basis[b * per_r + ic];
    W[idx] = acc;
}

__global__ __launch_bounds__(256) void edge_scatter(
        const float* __restrict__ W,
        const int* __restrict__ gnode,
        const int* __restrict__ snode,
        const int* __restrict__ fidx,
        const float* __restrict__ cj,
        float* __restrict__ h) {
    const int r = blockIdx.y;
    long tid = (long)blockIdx.x * blockDim.x + threadIdx.x;
    const int lane = (int)(tid & 31);
    const long e = tid >> 5;
    if (e >= kE) return;
    const int g = gnode[(long)r * kE + e];
    const int s = snode[(long)r * kE + e];
    const int i0 = fidx[g * 3 + 0];
    const int i1 = fidx[g * 3 + 1];
    const int i2 = fidx[g * 3 + 2];
    const float c = cj[g];
    const float* Wr = W + (size_t)r * kIn * kMsg;
    float* outp = h + (size_t)s * kAgg;
    atomicAdd(&outp[lane],            Wr[(size_t)i0 * kMsg + lane] * c);
    atomicAdd(&outp[kMsg + lane],     Wr[(size_t)i1 * kMsg + lane] * c);
    atomicAdd(&outp[2 * kMsg + lane], Wr[(size_t)i2 * kMsg + lane] * c);
}

__global__ __launch_bounds__(256) void fc_fused(const float* __restrict__ h,
                                                const float* __restrict__ ci,
                                                const float* __restrict__ w_fc,
                                                const float* __restrict__ b_fc,
                                                float* __restrict__ out, int nrows) {
    __shared__ float ws[kAgg * kOut];
    __shared__ float bs[kOut];
    const int lt = threadIdx.y * blockDim.x + threadIdx.x;
    for (int i = lt; i < kAgg * kOut; i += blockDim.x * blockDim.y)
        ws[i] = w_fc[i];
    if (lt < kOut) bs[lt] = b_fc[lt];
    __syncthreads();
    const int row = blockIdx.x * blockDim.y + threadIdx.y;
    if (row >= nrows) return;
    const int col = threadIdx.x;
    const float c = ci[row];
    const float* hr = h + (size_t)row * kAgg;
    float acc = bs[col];
#pragma unroll 8
    for (int k = 0; k < kAgg; ++k) {
        float a = hr[k] * c;
        a = (a >= 0.f) ? a : kSlope * a;
        acc += a * ws[k * kOut + col];
    }
    out[(size_t)row * kOut + col] = acc;
}

extern "C" void kernel_launch(void* const* d_in, const int* in_sizes, int n_in,
                              void* d_out, int out_size, void* d_ws, size_t ws_size,
                              hipStream_t stream) {
    const int*   drug_idx = (const int*)d_in[0];
    const int*   dis_idx  = (const int*)d_in[1];
    const int*   edge_src = (const int*)d_in[2];
    const int*   edge_dst = (const int*)d_in[3];
    const float* cj_drug  = (const float*)d_in[4];
    const float* ci_drug  = (const float*)d_in[5];
    const float* cj_dis   = (const float*)d_in[6];
    const float* ci_dis   = (const float*)d_in[7];
    const float* att      = (const float*)d_in[8];
    const float* basis    = (const float*)d_in[9];
    const float* w_fc     = (const float*)d_in[10];
    const float* b_fc     = (const float*)d_in[11];
    float* out = (float*)d_out;

    auto align256 = [](size_t x) { return (x + 255) & ~(size_t)255; };
    const size_t Wb    = align256((size_t)kR * kIn * kMsg * sizeof(float));     // 512 KB
    const size_t bcB   = align256((size_t)kNBuck * sizeof(int));
    const size_t ocB   = align256(sizeof(int));
    const size_t oeB   = align256((size_t)kOvfCap * sizeof(unsigned));          // 16 KB
    const size_t obB   = align256((size_t)kOvfCap * sizeof(int));               // 16 KB
    const size_t binB  = align256((size_t)kNBuck * kSegCap * sizeof(unsigned)); // ~13.88 MB
    const size_t needNew = Wb + bcB + ocB + oeB + obB + binB;                   // ~14.44 MB

    char* p = (char*)d_ws;
    float*    W      = (float*)p;        p += Wb;
    int*      bcur   = (int*)p;          p += bcB;
    int*      ovfCnt = (int*)p;          p += ocB;
    unsigned* ovfE   = (unsigned*)p;     p += oeB;
    int*      ovfB   = (int*)p;          p += obB;
    unsigned* bin    = (unsigned*)p;

    if (ws_size >= needNew) {
        setup_all<<<dim3(516), 256, 0, stream>>>(att, basis, W, bcur, ovfCnt);
        bin_pass<<<dim3(kBinBlocks), 1024, 0, stream>>>(edge_src, edge_dst,
                                                        bcur, bin, ovfCnt, ovfE, ovfB);
        ovf_drain<<<dim3((kOvfCap + 255) / 256), 256, 0, stream>>>(bcur, bin,
                                                                   ovfCnt, ovfE, ovfB);
        gather_fused<<<dim3(kNBuck), 512, 0, stream>>>(bin, bcur, ovfCnt, ovfE, ovfB,
                                                       W, drug_idx, dis_idx,
                                                       cj_drug, cj_dis,
                                                       ci_drug, ci_dis,
                                                       w_fc, b_fc, out);
    } else {
        // fallback: R1 phased atomic-scatter path (needs ~19.7 MB)
        build_W_fb<<<dim3((kR * kIn * kMsg + 255) / 256), 256, 0, stream>>>(att, basis, W);
        const size_t hB = (size_t)kNDrug * kAgg * sizeof(float);
        float* h = (float*)((char*)d_ws + Wb);
        const int scat_blocks = (int)(((long)kE * 32 + 255) / 256);
        const dim3 scat_grid(scat_blocks, kR);
        hipMemsetAsync(h, 0, hB, stream);
        edge_scatter<<<scat_grid, 256, 0, stream>>>(W, edge_dst, edge_src,
                                                    dis_idx, cj_dis, h);
        fc_fused<<<dim3((kNDrug + 3) / 4), dim3(64, 4), 0, stream>>>(
            h, ci_drug, w_fc, b_fc, out, kNDrug);
        hipMemsetAsync(h, 0, hB, stream);
        edge_scatter<<<scat_grid, 256, 0, stream>>>(W, edge_src, edge_dst,
                                                    drug_idx, cj_drug, h);
        fc_fused<<<dim3((kNDis + 3) / 4), dim3(64, 4), 0, stream>>>(
            h, ci_dis, w_fc, b_fc, out + (size_t)kNDrug * kOut, kNDis);
    }
}